// Round 8
// baseline (99.810 us; speedup 1.0000x reference)
//
#include <hip/hip_runtime.h>
#include <math.h>

#define K1 17
#define SEG_F (K1 * 256)          // 4352 elems per segment-array (permuted: elem 4*lane+j at j*64+lane)
#define PART_F (2 * SEG_F + 32)   // per-block partial region (dp sums, cf sums, counts) in floats
#define NGRP 8

#define SCALE_SUM 65536.0f
#define INV_SUM   (1.0f / 65536.0f)
#define SCALE_L   8192.0f
#define INV_L     (1.0f / 8192.0f)

// ws offsets in 4-byte units
#define GRED_BASE 0                           // NGRP * 2*SEG_F floats
#define MU_BASE   (NGRP * 2 * SEG_F)          // 69632: mu_dp[SEG_F], mu_cf[SEG_F] (NATURAL layout)
#define GCNT_OFF  (MU_BASE + 2 * SEG_F)       // 78336: K1 floats
#define LT_OFF    (GCNT_OFF + K1)             // K1 int accumulators
#define LC_OFF    (LT_OFF + K1)               // K1 int accumulators
#define DONE_OFF  (LC_OFF + K1)               // 1 int completion counter
#define PART_BASE 78400

// ---- wave64 sum via DPP (VALU-speed) ----
template <int CTRL, int RMASK>
__device__ __forceinline__ float dpp_add(float x) {
    int t = __builtin_amdgcn_update_dpp(0, __float_as_int(x), CTRL, RMASK, 0xf, false);
    return x + __int_as_float(t);
}
__device__ __forceinline__ float wave_sum_nb(float x) {   // total lands in lane 63 (no broadcast)
    x = dpp_add<0x111, 0xf>(x);
    x = dpp_add<0x112, 0xf>(x);
    x = dpp_add<0x114, 0xf>(x);
    x = dpp_add<0x118, 0xf>(x);
    x = dpp_add<0x142, 0xa>(x);
    x = dpp_add<0x143, 0xc>(x);
    return x;
}
__device__ __forceinline__ float wave_sum(float x) {      // broadcast to all lanes
    return __int_as_float(__builtin_amdgcn_readlane(__float_as_int(wave_sum_nb(x)), 63));
}
__device__ __forceinline__ float dot4s(const float4 v) {
    return v.x * v.x + v.y * v.y + v.z * v.z + v.w * v.w;
}
// softplus(x) = max(x,0) + ln(1+exp(-|x|)) via native v_exp/v_log (log2-based)
__device__ __forceinline__ float softplus_f(float x) {
    const float a = -fabsf(x) * 1.4426950408889634f;
    float e; asm("v_exp_f32 %0, %1" : "=v"(e) : "v"(a));
    float l; asm("v_log_f32 %0, %1" : "=v"(l) : "v"(1.0f + e));
    return fmaxf(x, 0.0f) + l * 0.6931471805599453f;
}
__device__ __forceinline__ float rsq_f(float x) {
    float r; asm("v_rsq_f32 %0, %1" : "=v"(r) : "v"(x));
    return r;
}

// ---- Pass 1: row-normalize both arrays, fixed-point segment-sum in LDS, write float partials ----
__device__ __forceinline__ void kA_commit(int* __restrict__ s, const float4 v, const float4 w,
                                          float nd, float nc, int l, int lane)
{
    const float f = SCALE_SUM * rsq_f(fmaxf(nd, 1e-24f));
    const float g = SCALE_SUM * rsq_f(fmaxf(nc, 1e-24f));
    int* a = s + l * 256 + lane;   // banks lane%32, 2 lanes/bank distinct addr = free
    atomicAdd(a,       (int)(v.x * f));
    atomicAdd(a + 64,  (int)(v.y * f));
    atomicAdd(a + 128, (int)(v.z * f));
    atomicAdd(a + 192, (int)(v.w * f));
    int* b = a + SEG_F;
    atomicAdd(b,       (int)(w.x * g));
    atomicAdd(b + 64,  (int)(w.y * g));
    atomicAdd(b + 128, (int)(w.z * g));
    atomicAdd(b + 192, (int)(w.w * g));
}

__global__ __launch_bounds__(1024) void kA(const float4* __restrict__ dp, const float4* __restrict__ cf,
                                           const int* __restrict__ mask, float* __restrict__ part,
                                           int nPart, int nRows)
{
    __shared__ int s[2 * SEG_F];
    __shared__ int hist[K1];
    const int tid = threadIdx.x;
    for (int i = tid; i < 2 * SEG_F; i += 1024) s[i] = 0;
    if (tid < K1) hist[tid] = 0;
    __syncthreads();

    const int lane = tid & 63;
    const int wid = tid >> 6;                       // 0..15
    const int rpb = (nRows + nPart - 1) / nPart;    // rows per block (contiguous tile)
    const int base = blockIdx.x * rpb;
    const int end = (base + rpb < nRows) ? base + rpb : nRows;

    int r = base + wid;
    for (; r + 16 < end; r += 32) {                 // unroll-2: rows r, r+16
        const int l0 = mask[r], l1 = mask[r + 16];
        const float4 v0 = dp[(size_t)r * 64 + lane];
        const float4 w0 = cf[(size_t)r * 64 + lane];
        const float4 v1 = dp[(size_t)(r + 16) * 64 + lane];
        const float4 w1 = cf[(size_t)(r + 16) * 64 + lane];
        const float nd0 = wave_sum(dot4s(v0));
        const float nc0 = wave_sum(dot4s(w0));
        const float nd1 = wave_sum(dot4s(v1));
        const float nc1 = wave_sum(dot4s(w1));
        kA_commit(s, v0, w0, nd0, nc0, l0, lane);
        kA_commit(s, v1, w1, nd1, nc1, l1, lane);
        if (lane == 0) { atomicAdd(&hist[l0], 1); atomicAdd(&hist[l1], 1); }
    }
    for (; r < end; r += 16) {
        const int l0 = mask[r];
        const float4 v0 = dp[(size_t)r * 64 + lane];
        const float4 w0 = cf[(size_t)r * 64 + lane];
        const float nd0 = wave_sum(dot4s(v0));
        const float nc0 = wave_sum(dot4s(w0));
        kA_commit(s, v0, w0, nd0, nc0, l0, lane);
        if (lane == 0) atomicAdd(&hist[l0], 1);
    }
    __syncthreads();
    float* outp = part + (size_t)blockIdx.x * PART_F;
    for (int i = tid; i < 2 * SEG_F; i += 1024) outp[i] = (float)s[i] * INV_SUM;
    if (tid < K1) outp[2 * SEG_F + tid] = (float)hist[tid];
}

// ---- stage-1 reduce of partials: [nPart][PART_F] -> [NGRP][2*SEG_F] ----
__global__ __launch_bounds__(256) void kRed(const float* __restrict__ part, float* __restrict__ gred, int nPart)
{
    const int col = blockIdx.x * 256 + threadIdx.x;   // 0..8703 (34 blocks)
    const int g = blockIdx.y;
    const int per = nPart / NGRP;
    const float* p = part + (size_t)g * per * PART_F + col;
    float acc = 0.0f;
    for (int b = 0; b < per; ++b) acc += p[(size_t)b * PART_F];
    gred[g * (2 * SEG_F) + col] = acc;
}

// ---- stage-2: finish sums, normalize means; write mu in NATURAL layout; zero loss accs ----
__global__ __launch_bounds__(256) void k_mu(float* __restrict__ ws, int nPart)
{
    const int k = blockIdx.x, t = threadIdx.x;
    if (k == 0 && t < 2 * K1 + 1) ((int*)ws)[LT_OFF + t] = 0;   // LT, LC, DONE
    __shared__ float C[256];
    float c = 0.0f;
    for (int b = t; b < nPart; b += 256) c += ws[PART_BASE + (size_t)b * PART_F + 2 * SEG_F + k];
    C[t] = c; __syncthreads();
    for (int s2 = 128; s2 > 0; s2 >>= 1) { if (t < s2) C[t] += C[t + s2]; __syncthreads(); }
    const float cnt = C[0];
    const float safe = fmaxf(cnt, 1.0f);
    float sd = 0.0f, sc = 0.0f;
    #pragma unroll
    for (int g = 0; g < NGRP; ++g) {
        sd += ws[GRED_BASE + g * 2 * SEG_F + k * 256 + t];
        sc += ws[GRED_BASE + g * 2 * SEG_F + SEG_F + k * 256 + t];
    }
    const float md = sd / safe, mc = sc / safe;
    __shared__ float A[256], B[256];
    A[t] = md * md; B[t] = mc * mc;
    __syncthreads();
    for (int s2 = 128; s2 > 0; s2 >>= 1) { if (t < s2) { A[t] += A[t + s2]; B[t] += B[t + s2]; } __syncthreads(); }
    const float id = 1.0f / fmaxf(sqrtf(A[0]), 1e-12f);
    const float ic = 1.0f / fmaxf(sqrtf(B[0]), 1e-12f);
    // de-permute: slot t holds element d = 4*(t%64) + t/64
    const int dnat = 4 * (t & 63) + (t >> 6);
    ws[MU_BASE + k * 256 + dnat]         = md * id;
    ws[MU_BASE + SEG_F + k * 256 + dnat] = mc * ic;
    if (t == 0) ws[GCNT_OFF + k] = cnt;
}

// ---- Pass 2: per-pixel losses -> fixed-point per-segment sums; last block finalizes ----
__device__ __forceinline__ void row_part(const float4 v, const float4 w, int l, int lane,
                                         const float4* __restrict__ mud, const float4* __restrict__ muc,
                                         const float4 bd, const float4 bc,
                                         float& nd, float& nc, float& dd, float& dc)
{
    const float4 md = mud[l * 64 + lane];
    const float4 mc = muc[l * 64 + lane];
    nd = dot4s(v);
    nc = dot4s(w);
    // dd partial of (neg - pos) = v.(bg - mu_label); dc partial of (oth - pos) = w.(mu_label - bg)
    dd = v.x * (bd.x - md.x) + v.y * (bd.y - md.y) + v.z * (bd.z - md.z) + v.w * (bd.w - md.w);
    dc = w.x * (mc.x - bc.x) + w.y * (mc.y - bc.y) + w.z * (mc.z - bc.z) + w.w * (mc.w - bc.w);
}
__device__ __forceinline__ void row_commit(float nd, float nc, float dd, float dc, int l, int tid63,
                                           int* __restrict__ lt, int* __restrict__ lc)
{
    const float invd = rsq_f(fmaxf(nd, 1e-24f));
    const float invc = rsq_f(fmaxf(nc, 1e-24f));
    const float xt = dd * invd * (1.0f / 0.07f);
    const float xc = dc * invc * (1.0f / 0.07f);
    const float plt = softplus_f(xt);
    const float plc = softplus_f(xc);
    if (tid63) {   // lane 63 holds the true sums
        atomicAdd(&lt[l], (int)(plt * SCALE_L + 0.5f));   // softplus >= 0 -> trunc+0.5 = round
        atomicAdd(&lc[l], (int)(plc * SCALE_L + 0.5f));
    }
}

__global__ __launch_bounds__(512) void k_loss(const float4* __restrict__ dp, const float4* __restrict__ cf,
                                              const int* __restrict__ mask, float* __restrict__ ws,
                                              float* __restrict__ out, int nBlocks, int nRows)
{
    __shared__ float4 mud[SEG_F / 4], muc[SEG_F / 4];   // natural layout: mud[k*64+lane] = elems 4lane..4lane+3
    __shared__ int lt[K1], lc[K1];
    const int tid = threadIdx.x;
    const float4* musrc = (const float4*)(ws + MU_BASE);
    for (int i = tid; i < SEG_F / 4; i += 512) { mud[i] = musrc[i]; muc[i] = musrc[SEG_F / 4 + i]; }
    if (tid < K1) { lt[tid] = 0; lc[tid] = 0; }
    __syncthreads();

    const int lane = tid & 63;
    const int wid = tid >> 6;                         // 0..7
    const int rpb = (nRows + nBlocks - 1) / nBlocks;  // contiguous tile per block
    const int base = blockIdx.x * rpb;
    const int end = (base + rpb < nRows) ? base + rpb : nRows;
    const int isl63 = (lane == 63);

    const float4 bd = mud[lane];    // loop-invariant background mu
    const float4 bc = muc[lane];

    int r = base + wid;
    for (; r + 8 < end; r += 16) {                    // unroll-2: rows r, r+8
        const int l0 = mask[r], l1 = mask[r + 8];
        const float4 v0 = dp[(size_t)r * 64 + lane];
        const float4 w0 = cf[(size_t)r * 64 + lane];
        const float4 v1 = dp[(size_t)(r + 8) * 64 + lane];
        const float4 w1 = cf[(size_t)(r + 8) * 64 + lane];
        float nd0, nc0, dd0, dc0, nd1, nc1, dd1, dc1;
        row_part(v0, w0, l0, lane, mud, muc, bd, bc, nd0, nc0, dd0, dc0);
        row_part(v1, w1, l1, lane, mud, muc, bd, bc, nd1, nc1, dd1, dc1);
        nd0 = wave_sum_nb(nd0); nc0 = wave_sum_nb(nc0); dd0 = wave_sum_nb(dd0); dc0 = wave_sum_nb(dc0);
        nd1 = wave_sum_nb(nd1); nc1 = wave_sum_nb(nc1); dd1 = wave_sum_nb(dd1); dc1 = wave_sum_nb(dc1);
        row_commit(nd0, nc0, dd0, dc0, l0, isl63, lt, lc);
        row_commit(nd1, nc1, dd1, dc1, l1, isl63, lt, lc);
    }
    for (; r < end; r += 8) {
        const int l0 = mask[r];
        const float4 v0 = dp[(size_t)r * 64 + lane];
        const float4 w0 = cf[(size_t)r * 64 + lane];
        float nd0, nc0, dd0, dc0;
        row_part(v0, w0, l0, lane, mud, muc, bd, bc, nd0, nc0, dd0, dc0);
        nd0 = wave_sum_nb(nd0); nc0 = wave_sum_nb(nc0); dd0 = wave_sum_nb(dd0); dc0 = wave_sum_nb(dc0);
        row_commit(nd0, nc0, dd0, dc0, l0, isl63, lt, lc);
    }
    __syncthreads();
    int* LT = (int*)ws + LT_OFF;
    int* LC = (int*)ws + LC_OFF;
    if (tid < K1) {
        atomicAdd(&LT[tid], lt[tid]);
        atomicAdd(&LC[tid], lc[tid]);
    }
    __syncthreads();   // block's global atomics drained before barrier exits
    if (tid == 0) {
        __threadfence();
        const int prev = atomicAdd((int*)ws + DONE_OFF, 1);
        if (prev == nBlocks - 1) {   // last block: all adds complete & visible
            __threadfence();
            float vt = 0.0f, vc = 0.0f, nv = 0.0f;
            for (int k = 1; k < K1; ++k) {
                const float cnt = ws[GCNT_OFF + k];
                if (cnt >= 3.0f) {   // MIN_PIXELS
                    const float safe = fmaxf(cnt, 1.0f);
                    vt += (float)atomicAdd(&LT[k], 0) * INV_L / safe;   // atomic read (L2-coherent)
                    vc += (float)atomicAdd(&LC[k], 0) * INV_L / safe;
                    nv += 1.0f;
                }
            }
            const float n = fmaxf(nv, 1.0f);
            out[0] = vt / n + 0.5f * (vc / n);   // LAMBDA_CF = 0.5
        }
    }
}

extern "C" void kernel_launch(void* const* d_in, const int* in_sizes, int n_in,
                              void* d_out, int out_size, void* d_ws, size_t ws_size,
                              hipStream_t stream)
{
    const float4* dp = (const float4*)d_in[0];
    const float4* cf = (const float4*)d_in[1];
    const int* mask  = (const int*)d_in[2];
    float* ws  = (float*)d_ws;
    float* out = (float*)d_out;
    const int nRows = in_sizes[2];

    long availF = (long)(ws_size / 4) - PART_BASE;
    int nPart = (int)(availF / PART_F);
    if (nPart > 256) nPart = 256;
    nPart &= ~7;            // multiple of NGRP
    if (nPart < 8) nPart = 8;

    kA<<<nPart, 1024, 0, stream>>>(dp, cf, mask, ws + PART_BASE, nPart, nRows);
    kRed<<<dim3(34, NGRP), 256, 0, stream>>>(ws + PART_BASE, ws + GRED_BASE, nPart);
    k_mu<<<K1, 256, 0, stream>>>(ws, nPart);
    const int nB3 = 1024;
    k_loss<<<nB3, 512, 0, stream>>>(dp, cf, mask, ws, out, nB3, nRows);
}

// Round 9
// 80.787 us; speedup vs baseline: 1.2355x; 1.2355x over previous
//
#include <hip/hip_runtime.h>
#include <math.h>

#define K1 17
#define SEG_F (K1 * 256)          // 4352 elems per segment-array (permuted: elem 4*lane+j at j*64+lane)
#define PART_F (2 * SEG_F + 32)   // per-block partial region in floats
#define NGRP 8
#define NPART 256

#define SCALE_SUM 65536.0f
#define INV_SUM   (1.0f / 65536.0f)
#define SCALE_L   8192.0f
#define INV_L     (1.0f / 8192.0f)
#define FP8_SCALE 16.0f
#define TAU_INV   (1.0f / 0.07f)

// ws offsets in 4-byte units
#define GRED_BASE 0                           // NGRP * 2*SEG_F floats
#define MU_BASE   (NGRP * 2 * SEG_F)          // 69632: DIFF tables (bg-k for dp, k-bg for cf), NATURAL layout
#define GCNT_OFF  (MU_BASE + 2 * SEG_F)       // K1 floats
#define LT_OFF    (GCNT_OFF + K1)             // K1 int accumulators
#define LC_OFF    (LT_OFF + K1)               // K1 int accumulators
#define PART_BASE 78400
#define FP8D_BASE (PART_BASE + NPART * PART_F)   // 2314816 (u32 units)

typedef float v2f __attribute__((ext_vector_type(2)));

// ---- wave64 sum via DPP ----
template <int CTRL, int RMASK>
__device__ __forceinline__ float dpp_add(float x) {
    int t = __builtin_amdgcn_update_dpp(0, __float_as_int(x), CTRL, RMASK, 0xf, false);
    return x + __int_as_float(t);
}
__device__ __forceinline__ float wave_sum_nb(float x) {   // total lands in lane 63
    x = dpp_add<0x111, 0xf>(x);
    x = dpp_add<0x112, 0xf>(x);
    x = dpp_add<0x114, 0xf>(x);
    x = dpp_add<0x118, 0xf>(x);
    x = dpp_add<0x142, 0xa>(x);
    x = dpp_add<0x143, 0xc>(x);
    return x;
}
__device__ __forceinline__ float wave_sum(float x) {      // broadcast
    return __int_as_float(__builtin_amdgcn_readlane(__float_as_int(wave_sum_nb(x)), 63));
}
__device__ __forceinline__ float dot4s(const float4 v) {
    return v.x * v.x + v.y * v.y + v.z * v.z + v.w * v.w;
}
__device__ __forceinline__ float softplus_f(float x) {
    const float a = -fabsf(x) * 1.4426950408889634f;
    float e; asm("v_exp_f32 %0, %1" : "=v"(e) : "v"(a));
    float l; asm("v_log_f32 %0, %1" : "=v"(l) : "v"(1.0f + e));
    return fmaxf(x, 0.0f) + l * 0.6931471805599453f;
}
__device__ __forceinline__ float rsq_f(float x) {
    float r; asm("v_rsq_f32 %0, %1" : "=v"(r) : "v"(x));
    return r;
}

// ---- Pass 1: normalize rows, fixed-point segment sums in LDS, optional fp8 write-out ----
template <bool W8>
__device__ __forceinline__ void kA_commit(int* __restrict__ s, const float4 v, const float4 w,
                                          float nd, float nc, int l, int lane,
                                          unsigned* __restrict__ q8d, unsigned* __restrict__ q8c)
{
    const float ir = rsq_f(fmaxf(nd, 1e-24f));
    const float jr = rsq_f(fmaxf(nc, 1e-24f));
    const float f = SCALE_SUM * ir;
    const float g = SCALE_SUM * jr;
    int* a = s + l * 256 + lane;   // permuted layout: banks lane%32, 2-way = free
    atomicAdd(a,       (int)(v.x * f));
    atomicAdd(a + 64,  (int)(v.y * f));
    atomicAdd(a + 128, (int)(v.z * f));
    atomicAdd(a + 192, (int)(v.w * f));
    int* b = a + SEG_F;
    atomicAdd(b,       (int)(w.x * g));
    atomicAdd(b + 64,  (int)(w.y * g));
    atomicAdd(b + 128, (int)(w.z * g));
    atomicAdd(b + 192, (int)(w.w * g));
    if (W8) {
        const float fe = FP8_SCALE * ir;
        const float ge = FP8_SCALE * jr;
        int pd = __builtin_amdgcn_cvt_pk_fp8_f32(v.x * fe, v.y * fe, 0, false);
        pd     = __builtin_amdgcn_cvt_pk_fp8_f32(v.z * fe, v.w * fe, pd, true);
        int pc = __builtin_amdgcn_cvt_pk_fp8_f32(w.x * ge, w.y * ge, 0, false);
        pc     = __builtin_amdgcn_cvt_pk_fp8_f32(w.z * ge, w.w * ge, pc, true);
        *q8d = (unsigned)pd;
        *q8c = (unsigned)pc;
    }
}

template <bool W8>
__global__ __launch_bounds__(1024) void kA(const float4* __restrict__ dp, const float4* __restrict__ cf,
                                           const int* __restrict__ mask, float* __restrict__ part,
                                           unsigned* __restrict__ qd, unsigned* __restrict__ qc,
                                           int nPart, int nRows)
{
    __shared__ int s[2 * SEG_F];
    __shared__ int hist[K1];
    const int tid = threadIdx.x;
    for (int i = tid; i < 2 * SEG_F; i += 1024) s[i] = 0;
    if (tid < K1) hist[tid] = 0;
    __syncthreads();

    const int lane = tid & 63;
    const int wid = tid >> 6;                       // 0..15
    const int rpb = (nRows + nPart - 1) / nPart;
    const int base = blockIdx.x * rpb;
    const int end = (base + rpb < nRows) ? base + rpb : nRows;

    int r = base + wid;
    for (; r + 16 < end; r += 32) {
        const int l0 = mask[r], l1 = mask[r + 16];
        const float4 v0 = dp[(size_t)r * 64 + lane];
        const float4 w0 = cf[(size_t)r * 64 + lane];
        const float4 v1 = dp[(size_t)(r + 16) * 64 + lane];
        const float4 w1 = cf[(size_t)(r + 16) * 64 + lane];
        const float nd0 = wave_sum(dot4s(v0));
        const float nc0 = wave_sum(dot4s(w0));
        const float nd1 = wave_sum(dot4s(v1));
        const float nc1 = wave_sum(dot4s(w1));
        kA_commit<W8>(s, v0, w0, nd0, nc0, l0, lane, qd + (size_t)r * 64 + lane,        qc + (size_t)r * 64 + lane);
        kA_commit<W8>(s, v1, w1, nd1, nc1, l1, lane, qd + (size_t)(r + 16) * 64 + lane, qc + (size_t)(r + 16) * 64 + lane);
        if (lane == 0) { atomicAdd(&hist[l0], 1); atomicAdd(&hist[l1], 1); }
    }
    for (; r < end; r += 16) {
        const int l0 = mask[r];
        const float4 v0 = dp[(size_t)r * 64 + lane];
        const float4 w0 = cf[(size_t)r * 64 + lane];
        const float nd0 = wave_sum(dot4s(v0));
        const float nc0 = wave_sum(dot4s(w0));
        kA_commit<W8>(s, v0, w0, nd0, nc0, l0, lane, qd + (size_t)r * 64 + lane, qc + (size_t)r * 64 + lane);
        if (lane == 0) atomicAdd(&hist[l0], 1);
    }
    __syncthreads();
    float* outp = part + (size_t)blockIdx.x * PART_F;
    for (int i = tid; i < 2 * SEG_F; i += 1024) outp[i] = (float)s[i] * INV_SUM;
    if (tid < K1) outp[2 * SEG_F + tid] = (float)hist[tid];
}

// ---- stage-1 reduce of partials ----
__global__ __launch_bounds__(256) void kRed(const float* __restrict__ part, float* __restrict__ gred, int nPart)
{
    const int col = blockIdx.x * 256 + threadIdx.x;   // 0..8703 (34 blocks)
    const int g = blockIdx.y;
    const int per = nPart / NGRP;
    const float* p = part + (size_t)g * per * PART_F + col;
    float acc = 0.0f;
    for (int b = 0; b < per; ++b) acc += p[(size_t)b * PART_F];
    gred[g * (2 * SEG_F) + col] = acc;
}

// ---- stage-2: normalize means; store DIFF tables (bg-k dp, k-bg cf) in NATURAL layout; zero loss accs ----
__global__ __launch_bounds__(256) void k_mu(float* __restrict__ ws, int nPart)
{
    const int k = blockIdx.x, t = threadIdx.x;
    if (k == 0 && t < 2 * K1) ((int*)ws)[LT_OFF + t] = 0;
    __shared__ float C[256];
    float c = 0.0f;
    for (int b = t; b < nPart; b += 256) c += ws[PART_BASE + (size_t)b * PART_F + 2 * SEG_F + k];
    C[t] = c; __syncthreads();
    for (int s2 = 128; s2 > 0; s2 >>= 1) { if (t < s2) C[t] += C[t + s2]; __syncthreads(); }
    const float cnt = C[0];
    __syncthreads();
    float c0 = 0.0f;
    for (int b = t; b < nPart; b += 256) c0 += ws[PART_BASE + (size_t)b * PART_F + 2 * SEG_F];
    C[t] = c0; __syncthreads();
    for (int s2 = 128; s2 > 0; s2 >>= 1) { if (t < s2) C[t] += C[t + s2]; __syncthreads(); }
    const float cnt0 = C[0];

    const float safek = fmaxf(cnt, 1.0f), safe0 = fmaxf(cnt0, 1.0f);
    float sdk = 0, sck = 0, sd0 = 0, sc0 = 0;
    #pragma unroll
    for (int g = 0; g < NGRP; ++g) {
        const float* gr = ws + GRED_BASE + g * 2 * SEG_F;
        sdk += gr[k * 256 + t];  sck += gr[SEG_F + k * 256 + t];
        sd0 += gr[t];            sc0 += gr[SEG_F + t];
    }
    const float mdk = sdk / safek, mck = sck / safek;
    const float md0 = sd0 / safe0, mc0 = sc0 / safe0;
    __shared__ float A[256], B[256];
    A[t] = mdk * mdk; B[t] = mck * mck;
    __syncthreads();
    for (int s2 = 128; s2 > 0; s2 >>= 1) { if (t < s2) { A[t] += A[t + s2]; B[t] += B[t + s2]; } __syncthreads(); }
    const float idk = 1.0f / fmaxf(sqrtf(A[0]), 1e-12f);
    const float ick = 1.0f / fmaxf(sqrtf(B[0]), 1e-12f);
    __syncthreads();
    A[t] = md0 * md0; B[t] = mc0 * mc0;
    __syncthreads();
    for (int s2 = 128; s2 > 0; s2 >>= 1) { if (t < s2) { A[t] += A[t + s2]; B[t] += B[t + s2]; } __syncthreads(); }
    const float id0 = 1.0f / fmaxf(sqrtf(A[0]), 1e-12f);
    const float ic0 = 1.0f / fmaxf(sqrtf(B[0]), 1e-12f);
    // de-permute: slot t holds element d = 4*(t%64) + t/64
    const int dnat = 4 * (t & 63) + (t >> 6);
    ws[MU_BASE + k * 256 + dnat]         = md0 * id0 - mdk * idk;   // dp: mu_bg - mu_k
    ws[MU_BASE + SEG_F + k * 256 + dnat] = mck * ick - mc0 * ic0;   // cf: mu_k - mu_bg
    if (t == 0) ws[GCNT_OFF + k] = cnt;
}

// ---- Pass 2 (fp8): unit rows, diff-mu dots only ----
__device__ __forceinline__ void q_commit(float dd, float dc, int l, int isl63,
                                         int* __restrict__ lt, int* __restrict__ lc)
{
    const float xt = dd * (TAU_INV / FP8_SCALE);
    const float xc = dc * (TAU_INV / FP8_SCALE);
    const float plt = softplus_f(xt);
    const float plc = softplus_f(xc);
    if (isl63) {
        atomicAdd(&lt[l], (int)(plt * SCALE_L + 0.5f));
        atomicAdd(&lc[l], (int)(plc * SCALE_L + 0.5f));
    }
}
__global__ __launch_bounds__(512) void k_loss8(const unsigned* __restrict__ qd, const unsigned* __restrict__ qc,
                                               const int* __restrict__ mask, float* __restrict__ ws,
                                               int nBlocks, int nRows)
{
    __shared__ float4 dmud[SEG_F / 4], dmuc[SEG_F / 4];
    __shared__ int lt[K1], lc[K1];
    const int tid = threadIdx.x;
    const float4* musrc = (const float4*)(ws + MU_BASE);
    for (int i = tid; i < SEG_F / 4; i += 512) { dmud[i] = musrc[i]; dmuc[i] = musrc[SEG_F / 4 + i]; }
    if (tid < K1) { lt[tid] = 0; lc[tid] = 0; }
    __syncthreads();

    const int lane = tid & 63;
    const int wid = tid >> 6;
    const int rpb = (nRows + nBlocks - 1) / nBlocks;
    const int base = blockIdx.x * rpb;
    const int end = (base + rpb < nRows) ? base + rpb : nRows;
    const int isl63 = (lane == 63);

    int r = base + wid;
    for (; r + 8 < end; r += 16) {
        const int l0 = mask[r], l1 = mask[r + 8];
        const unsigned a0 = qd[(size_t)r * 64 + lane],       b0 = qc[(size_t)r * 64 + lane];
        const unsigned a1 = qd[(size_t)(r + 8) * 64 + lane], b1 = qc[(size_t)(r + 8) * 64 + lane];
        const float4 D0 = dmud[l0 * 64 + lane], C0 = dmuc[l0 * 64 + lane];
        const float4 D1 = dmud[l1 * 64 + lane], C1 = dmuc[l1 * 64 + lane];
        const v2f al0 = __builtin_amdgcn_cvt_pk_f32_fp8((int)a0, false), ah0 = __builtin_amdgcn_cvt_pk_f32_fp8((int)a0, true);
        const v2f bl0 = __builtin_amdgcn_cvt_pk_f32_fp8((int)b0, false), bh0 = __builtin_amdgcn_cvt_pk_f32_fp8((int)b0, true);
        const v2f al1 = __builtin_amdgcn_cvt_pk_f32_fp8((int)a1, false), ah1 = __builtin_amdgcn_cvt_pk_f32_fp8((int)a1, true);
        const v2f bl1 = __builtin_amdgcn_cvt_pk_f32_fp8((int)b1, false), bh1 = __builtin_amdgcn_cvt_pk_f32_fp8((int)b1, true);
        float dd0 = al0.x * D0.x + al0.y * D0.y + ah0.x * D0.z + ah0.y * D0.w;
        float dc0 = bl0.x * C0.x + bl0.y * C0.y + bh0.x * C0.z + bh0.y * C0.w;
        float dd1 = al1.x * D1.x + al1.y * D1.y + ah1.x * D1.z + ah1.y * D1.w;
        float dc1 = bl1.x * C1.x + bl1.y * C1.y + bh1.x * C1.z + bh1.y * C1.w;
        dd0 = wave_sum_nb(dd0); dc0 = wave_sum_nb(dc0);
        dd1 = wave_sum_nb(dd1); dc1 = wave_sum_nb(dc1);
        q_commit(dd0, dc0, l0, isl63, lt, lc);
        q_commit(dd1, dc1, l1, isl63, lt, lc);
    }
    for (; r < end; r += 8) {
        const int l0 = mask[r];
        const unsigned a0 = qd[(size_t)r * 64 + lane], b0 = qc[(size_t)r * 64 + lane];
        const float4 D0 = dmud[l0 * 64 + lane], C0 = dmuc[l0 * 64 + lane];
        const v2f al0 = __builtin_amdgcn_cvt_pk_f32_fp8((int)a0, false), ah0 = __builtin_amdgcn_cvt_pk_f32_fp8((int)a0, true);
        const v2f bl0 = __builtin_amdgcn_cvt_pk_f32_fp8((int)b0, false), bh0 = __builtin_amdgcn_cvt_pk_f32_fp8((int)b0, true);
        float dd0 = al0.x * D0.x + al0.y * D0.y + ah0.x * D0.z + ah0.y * D0.w;
        float dc0 = bl0.x * C0.x + bl0.y * C0.y + bh0.x * C0.z + bh0.y * C0.w;
        dd0 = wave_sum_nb(dd0); dc0 = wave_sum_nb(dc0);
        q_commit(dd0, dc0, l0, isl63, lt, lc);
    }
    __syncthreads();
    if (tid < K1) {
        atomicAdd((int*)ws + LT_OFF + tid, lt[tid]);
        atomicAdd((int*)ws + LC_OFF + tid, lc[tid]);
    }
}

// ---- Pass 2 fallback (raw floats, diff-mu + norms) ----
__global__ __launch_bounds__(512) void k_lossraw(const float4* __restrict__ dp, const float4* __restrict__ cf,
                                                 const int* __restrict__ mask, float* __restrict__ ws,
                                                 int nBlocks, int nRows)
{
    __shared__ float4 dmud[SEG_F / 4], dmuc[SEG_F / 4];
    __shared__ int lt[K1], lc[K1];
    const int tid = threadIdx.x;
    const float4* musrc = (const float4*)(ws + MU_BASE);
    for (int i = tid; i < SEG_F / 4; i += 512) { dmud[i] = musrc[i]; dmuc[i] = musrc[SEG_F / 4 + i]; }
    if (tid < K1) { lt[tid] = 0; lc[tid] = 0; }
    __syncthreads();

    const int lane = tid & 63;
    const int wid = tid >> 6;
    const int rpb = (nRows + nBlocks - 1) / nBlocks;
    const int base = blockIdx.x * rpb;
    const int end = (base + rpb < nRows) ? base + rpb : nRows;
    const int isl63 = (lane == 63);

    for (int r = base + wid; r < end; r += 8) {
        const int l0 = mask[r];
        const float4 v0 = dp[(size_t)r * 64 + lane];
        const float4 w0 = cf[(size_t)r * 64 + lane];
        const float4 D0 = dmud[l0 * 64 + lane], C0 = dmuc[l0 * 64 + lane];
        float nd = dot4s(v0), nc = dot4s(w0);
        float dd = v0.x * D0.x + v0.y * D0.y + v0.z * D0.z + v0.w * D0.w;
        float dc = w0.x * C0.x + w0.y * C0.y + w0.z * C0.z + w0.w * C0.w;
        nd = wave_sum_nb(nd); nc = wave_sum_nb(nc);
        dd = wave_sum_nb(dd); dc = wave_sum_nb(dc);
        const float xt = dd * rsq_f(fmaxf(nd, 1e-24f)) * TAU_INV;
        const float xc = dc * rsq_f(fmaxf(nc, 1e-24f)) * TAU_INV;
        const float plt = softplus_f(xt);
        const float plc = softplus_f(xc);
        if (isl63) {
            atomicAdd(&lt[l0], (int)(plt * SCALE_L + 0.5f));
            atomicAdd(&lc[l0], (int)(plc * SCALE_L + 0.5f));
        }
    }
    __syncthreads();
    if (tid < K1) {
        atomicAdd((int*)ws + LT_OFF + tid, lt[tid]);
        atomicAdd((int*)ws + LC_OFF + tid, lc[tid]);
    }
}

// ---- finalize scalar ----
__global__ void k_final(const float* __restrict__ ws, float* __restrict__ out)
{
    const int t = threadIdx.x; // 64
    const int* LT = (const int*)ws + LT_OFF;
    const int* LC = (const int*)ws + LC_OFF;
    float vt = 0.0f, vc = 0.0f, nv = 0.0f;
    if (t >= 1 && t < K1) {
        const float cnt = ws[GCNT_OFF + t];
        if (cnt >= 3.0f) {  // MIN_PIXELS
            const float safe = fmaxf(cnt, 1.0f);
            vt = (float)LT[t] * INV_L / safe;
            vc = (float)LC[t] * INV_L / safe;
            nv = 1.0f;
        }
    }
    #pragma unroll
    for (int o = 32; o > 0; o >>= 1) {
        vt += __shfl_xor(vt, o, 64);
        vc += __shfl_xor(vc, o, 64);
        nv += __shfl_xor(nv, o, 64);
    }
    if (t == 0) {
        const float n = fmaxf(nv, 1.0f);
        out[0] = vt / n + 0.5f * (vc / n);  // LAMBDA_CF = 0.5
    }
}

extern "C" void kernel_launch(void* const* d_in, const int* in_sizes, int n_in,
                              void* d_out, int out_size, void* d_ws, size_t ws_size,
                              hipStream_t stream)
{
    const float4* dp = (const float4*)d_in[0];
    const float4* cf = (const float4*)d_in[1];
    const int* mask  = (const int*)d_in[2];
    float* ws  = (float*)d_ws;
    float* out = (float*)d_out;
    const int nRows = in_sizes[2];

    unsigned* qd = (unsigned*)ws + FP8D_BASE;
    unsigned* qc = qd + (size_t)nRows * 64;
    const bool use8 = (ws_size / 4) >= (size_t)FP8D_BASE + 2 * (size_t)nRows * 64;

    if (use8)
        kA<true><<<NPART, 1024, 0, stream>>>(dp, cf, mask, ws + PART_BASE, qd, qc, NPART, nRows);
    else
        kA<false><<<NPART, 1024, 0, stream>>>(dp, cf, mask, ws + PART_BASE, qd, qc, NPART, nRows);
    kRed<<<dim3(34, NGRP), 256, 0, stream>>>(ws + PART_BASE, ws + GRED_BASE, NPART);
    k_mu<<<K1, 256, 0, stream>>>(ws, NPART);
    const int nB3 = 1024;
    if (use8)
        k_loss8<<<nB3, 512, 0, stream>>>(qd, qc, mask, ws, nB3, nRows);
    else
        k_lossraw<<<nB3, 512, 0, stream>>>(dp, cf, mask, ws, nB3, nRows);
    k_final<<<1, 64, 0, stream>>>(ws, out);
}

// Round 10
// 80.602 us; speedup vs baseline: 1.2383x; 1.0023x over previous
//
#include <hip/hip_runtime.h>
#include <math.h>

#define K1 17
#define SEG_F (K1 * 256)          // 4352 elems per segment-array (permuted: elem 4*lane+j at j*64+lane)
#define PART_F (2 * SEG_F + 32)   // per-block partial region in floats
#define NGRP 8
#define NPART 256

#define SCALE_SUM 65536.0f
#define INV_SUM   (1.0f / 65536.0f)
#define SCALE_L   8192.0f
#define INV_L     (1.0f / 8192.0f)
#define FP8_SCALE 16.0f
#define TAU_INV   (1.0f / 0.07f)

// ws offsets in 4-byte units
#define GRED_BASE 0                           // NGRP * 2*SEG_F floats
#define MU_BASE   (NGRP * 2 * SEG_F)          // 69632: DIFF tables (bg-k for dp, k-bg for cf), NATURAL layout
#define GCNT_OFF  (MU_BASE + 2 * SEG_F)       // K1 floats
#define LT_OFF    (GCNT_OFF + K1)             // K1 int accumulators
#define LC_OFF    (LT_OFF + K1)               // K1 int accumulators
#define PART_BASE 78400
#define FP8D_BASE (PART_BASE + NPART * PART_F)   // u32 units; then nRows*64 uint2

typedef float v2f __attribute__((ext_vector_type(2)));

// ---- wave64 sum via DPP ----
template <int CTRL, int RMASK>
__device__ __forceinline__ float dpp_add(float x) {
    int t = __builtin_amdgcn_update_dpp(0, __float_as_int(x), CTRL, RMASK, 0xf, false);
    return x + __int_as_float(t);
}
__device__ __forceinline__ float wave_sum_nb(float x) {   // total lands in lane 63
    x = dpp_add<0x111, 0xf>(x);
    x = dpp_add<0x112, 0xf>(x);
    x = dpp_add<0x114, 0xf>(x);
    x = dpp_add<0x118, 0xf>(x);
    x = dpp_add<0x142, 0xa>(x);
    x = dpp_add<0x143, 0xc>(x);
    return x;
}
__device__ __forceinline__ float wave_sum(float x) {      // broadcast
    return __int_as_float(__builtin_amdgcn_readlane(__float_as_int(wave_sum_nb(x)), 63));
}
__device__ __forceinline__ float dot4s(const float4 v) {
    return v.x * v.x + v.y * v.y + v.z * v.z + v.w * v.w;
}
__device__ __forceinline__ float softplus_f(float x) {
    const float a = -fabsf(x) * 1.4426950408889634f;
    float e; asm("v_exp_f32 %0, %1" : "=v"(e) : "v"(a));
    float l; asm("v_log_f32 %0, %1" : "=v"(l) : "v"(1.0f + e));
    return fmaxf(x, 0.0f) + l * 0.6931471805599453f;
}
__device__ __forceinline__ float rsq_f(float x) {
    float r; asm("v_rsq_f32 %0, %1" : "=v"(r) : "v"(x));
    return r;
}

// ---- Pass 1: normalize rows, fixed-point segment sums in LDS, packed fp8 write-out ----
template <bool W8>
__device__ __forceinline__ void kA_commit(int* __restrict__ s, const float4 v, const float4 w,
                                          float nd, float nc, int l, int lane,
                                          uint2* __restrict__ q8)
{
    const float ir = rsq_f(fmaxf(nd, 1e-24f));
    const float jr = rsq_f(fmaxf(nc, 1e-24f));
    const float f = SCALE_SUM * ir;
    const float g = SCALE_SUM * jr;
    int* a = s + l * 256 + lane;   // permuted layout: banks lane%32, 2-way = free
    atomicAdd(a,       (int)(v.x * f));
    atomicAdd(a + 64,  (int)(v.y * f));
    atomicAdd(a + 128, (int)(v.z * f));
    atomicAdd(a + 192, (int)(v.w * f));
    int* b = a + SEG_F;
    atomicAdd(b,       (int)(w.x * g));
    atomicAdd(b + 64,  (int)(w.y * g));
    atomicAdd(b + 128, (int)(w.z * g));
    atomicAdd(b + 192, (int)(w.w * g));
    if (W8) {
        const float fe = FP8_SCALE * ir;
        const float ge = FP8_SCALE * jr;
        int pd = __builtin_amdgcn_cvt_pk_fp8_f32(v.x * fe, v.y * fe, 0, false);
        pd     = __builtin_amdgcn_cvt_pk_fp8_f32(v.z * fe, v.w * fe, pd, true);
        int pc = __builtin_amdgcn_cvt_pk_fp8_f32(w.x * ge, w.y * ge, 0, false);
        pc     = __builtin_amdgcn_cvt_pk_fp8_f32(w.z * ge, w.w * ge, pc, true);
        *q8 = make_uint2((unsigned)pd, (unsigned)pc);
    }
}

template <bool W8>
__global__ __launch_bounds__(1024) void kA(const float4* __restrict__ dp, const float4* __restrict__ cf,
                                           const int* __restrict__ mask, float* __restrict__ part,
                                           uint2* __restrict__ q, int nPart, int nRows)
{
    __shared__ int s[2 * SEG_F];
    __shared__ int hist[K1];
    const int tid = threadIdx.x;
    for (int i = tid; i < 2 * SEG_F; i += 1024) s[i] = 0;
    if (tid < K1) hist[tid] = 0;
    __syncthreads();

    const int lane = tid & 63;
    const int wid = tid >> 6;                       // 0..15
    const int rpb = (nRows + nPart - 1) / nPart;
    const int base = blockIdx.x * rpb;
    const int end = (base + rpb < nRows) ? base + rpb : nRows;

    int r = base + wid;
    for (; r + 16 < end; r += 32) {
        const int l0 = mask[r], l1 = mask[r + 16];
        const float4 v0 = dp[(size_t)r * 64 + lane];
        const float4 w0 = cf[(size_t)r * 64 + lane];
        const float4 v1 = dp[(size_t)(r + 16) * 64 + lane];
        const float4 w1 = cf[(size_t)(r + 16) * 64 + lane];
        const float nd0 = wave_sum(dot4s(v0));
        const float nc0 = wave_sum(dot4s(w0));
        const float nd1 = wave_sum(dot4s(v1));
        const float nc1 = wave_sum(dot4s(w1));
        kA_commit<W8>(s, v0, w0, nd0, nc0, l0, lane, q + (size_t)r * 64 + lane);
        kA_commit<W8>(s, v1, w1, nd1, nc1, l1, lane, q + (size_t)(r + 16) * 64 + lane);
        if (lane == 0) { atomicAdd(&hist[l0], 1); atomicAdd(&hist[l1], 1); }
    }
    for (; r < end; r += 16) {
        const int l0 = mask[r];
        const float4 v0 = dp[(size_t)r * 64 + lane];
        const float4 w0 = cf[(size_t)r * 64 + lane];
        const float nd0 = wave_sum(dot4s(v0));
        const float nc0 = wave_sum(dot4s(w0));
        kA_commit<W8>(s, v0, w0, nd0, nc0, l0, lane, q + (size_t)r * 64 + lane);
        if (lane == 0) atomicAdd(&hist[l0], 1);
    }
    __syncthreads();
    float* outp = part + (size_t)blockIdx.x * PART_F;
    for (int i = tid; i < 2 * SEG_F; i += 1024) outp[i] = (float)s[i] * INV_SUM;
    if (tid < K1) outp[2 * SEG_F + tid] = (float)hist[tid];
}

// ---- stage-1 reduce of partials ----
__global__ __launch_bounds__(256) void kRed(const float* __restrict__ part, float* __restrict__ gred, int nPart)
{
    const int col = blockIdx.x * 256 + threadIdx.x;   // 0..8703 (34 blocks)
    const int g = blockIdx.y;
    const int per = nPart / NGRP;
    const float* p = part + (size_t)g * per * PART_F + col;
    float acc = 0.0f;
    for (int b = 0; b < per; ++b) acc += p[(size_t)b * PART_F];
    gred[g * (2 * SEG_F) + col] = acc;
}

// ---- stage-2: normalize means; store DIFF tables (bg-k dp, k-bg cf) in NATURAL layout; zero loss accs ----
__global__ __launch_bounds__(256) void k_mu(float* __restrict__ ws, int nPart)
{
    const int k = blockIdx.x, t = threadIdx.x;
    if (k == 0 && t < 2 * K1) ((int*)ws)[LT_OFF + t] = 0;
    __shared__ float C[256];
    float c = 0.0f;
    for (int b = t; b < nPart; b += 256) c += ws[PART_BASE + (size_t)b * PART_F + 2 * SEG_F + k];
    C[t] = c; __syncthreads();
    for (int s2 = 128; s2 > 0; s2 >>= 1) { if (t < s2) C[t] += C[t + s2]; __syncthreads(); }
    const float cnt = C[0];
    __syncthreads();
    float c0 = 0.0f;
    for (int b = t; b < nPart; b += 256) c0 += ws[PART_BASE + (size_t)b * PART_F + 2 * SEG_F];
    C[t] = c0; __syncthreads();
    for (int s2 = 128; s2 > 0; s2 >>= 1) { if (t < s2) C[t] += C[t + s2]; __syncthreads(); }
    const float cnt0 = C[0];

    const float safek = fmaxf(cnt, 1.0f), safe0 = fmaxf(cnt0, 1.0f);
    float sdk = 0, sck = 0, sd0 = 0, sc0 = 0;
    #pragma unroll
    for (int g = 0; g < NGRP; ++g) {
        const float* gr = ws + GRED_BASE + g * 2 * SEG_F;
        sdk += gr[k * 256 + t];  sck += gr[SEG_F + k * 256 + t];
        sd0 += gr[t];            sc0 += gr[SEG_F + t];
    }
    const float mdk = sdk / safek, mck = sck / safek;
    const float md0 = sd0 / safe0, mc0 = sc0 / safe0;
    __shared__ float A[256], B[256];
    A[t] = mdk * mdk; B[t] = mck * mck;
    __syncthreads();
    for (int s2 = 128; s2 > 0; s2 >>= 1) { if (t < s2) { A[t] += A[t + s2]; B[t] += B[t + s2]; } __syncthreads(); }
    const float idk = 1.0f / fmaxf(sqrtf(A[0]), 1e-12f);
    const float ick = 1.0f / fmaxf(sqrtf(B[0]), 1e-12f);
    __syncthreads();
    A[t] = md0 * md0; B[t] = mc0 * mc0;
    __syncthreads();
    for (int s2 = 128; s2 > 0; s2 >>= 1) { if (t < s2) { A[t] += A[t + s2]; B[t] += B[t + s2]; } __syncthreads(); }
    const float id0 = 1.0f / fmaxf(sqrtf(A[0]), 1e-12f);
    const float ic0 = 1.0f / fmaxf(sqrtf(B[0]), 1e-12f);
    // de-permute: slot t holds element d = 4*(t%64) + t/64
    const int dnat = 4 * (t & 63) + (t >> 6);
    ws[MU_BASE + k * 256 + dnat]         = md0 * id0 - mdk * idk;   // dp: mu_bg - mu_k
    ws[MU_BASE + SEG_F + k * 256 + dnat] = mck * ick - mc0 * ic0;   // cf: mu_k - mu_bg
    if (t == 0) ws[GCNT_OFF + k] = cnt;
}

// ---- Pass 2 (fp8, packed): unit rows, diff-mu dots only ----
__device__ __forceinline__ void q_commit(float dd, float dc, int l, int isl63,
                                         int* __restrict__ lt, int* __restrict__ lc)
{
    const float xt = dd * (TAU_INV / FP8_SCALE);
    const float xc = dc * (TAU_INV / FP8_SCALE);
    const float plt = softplus_f(xt);
    const float plc = softplus_f(xc);
    if (isl63) {
        atomicAdd(&lt[l], (int)(plt * SCALE_L + 0.5f));
        atomicAdd(&lc[l], (int)(plc * SCALE_L + 0.5f));
    }
}
__global__ __launch_bounds__(512) void k_loss8(const uint2* __restrict__ q,
                                               const int* __restrict__ mask, float* __restrict__ ws,
                                               int nBlocks, int nRows)
{
    __shared__ float4 dmud[SEG_F / 4], dmuc[SEG_F / 4];
    __shared__ int lt[K1], lc[K1];
    const int tid = threadIdx.x;
    const float4* musrc = (const float4*)(ws + MU_BASE);
    for (int i = tid; i < SEG_F / 4; i += 512) { dmud[i] = musrc[i]; dmuc[i] = musrc[SEG_F / 4 + i]; }
    if (tid < K1) { lt[tid] = 0; lc[tid] = 0; }
    __syncthreads();

    const int lane = tid & 63;
    const int wid = tid >> 6;
    const int rpb = (nRows + nBlocks - 1) / nBlocks;
    const int base = blockIdx.x * rpb;
    const int end = (base + rpb < nRows) ? base + rpb : nRows;
    const int isl63 = (lane == 63);

    int r = base + wid;
    for (; r + 8 < end; r += 16) {
        const int l0 = mask[r], l1 = mask[r + 8];
        const uint2 q0 = q[(size_t)r * 64 + lane];
        const uint2 q1 = q[(size_t)(r + 8) * 64 + lane];
        const float4 D0 = dmud[l0 * 64 + lane], C0 = dmuc[l0 * 64 + lane];
        const float4 D1 = dmud[l1 * 64 + lane], C1 = dmuc[l1 * 64 + lane];
        const v2f al0 = __builtin_amdgcn_cvt_pk_f32_fp8((int)q0.x, false), ah0 = __builtin_amdgcn_cvt_pk_f32_fp8((int)q0.x, true);
        const v2f bl0 = __builtin_amdgcn_cvt_pk_f32_fp8((int)q0.y, false), bh0 = __builtin_amdgcn_cvt_pk_f32_fp8((int)q0.y, true);
        const v2f al1 = __builtin_amdgcn_cvt_pk_f32_fp8((int)q1.x, false), ah1 = __builtin_amdgcn_cvt_pk_f32_fp8((int)q1.x, true);
        const v2f bl1 = __builtin_amdgcn_cvt_pk_f32_fp8((int)q1.y, false), bh1 = __builtin_amdgcn_cvt_pk_f32_fp8((int)q1.y, true);
        float dd0 = al0.x * D0.x + al0.y * D0.y + ah0.x * D0.z + ah0.y * D0.w;
        float dc0 = bl0.x * C0.x + bl0.y * C0.y + bh0.x * C0.z + bh0.y * C0.w;
        float dd1 = al1.x * D1.x + al1.y * D1.y + ah1.x * D1.z + ah1.y * D1.w;
        float dc1 = bl1.x * C1.x + bl1.y * C1.y + bh1.x * C1.z + bh1.y * C1.w;
        dd0 = wave_sum_nb(dd0); dc0 = wave_sum_nb(dc0);
        dd1 = wave_sum_nb(dd1); dc1 = wave_sum_nb(dc1);
        q_commit(dd0, dc0, l0, isl63, lt, lc);
        q_commit(dd1, dc1, l1, isl63, lt, lc);
    }
    for (; r < end; r += 8) {
        const int l0 = mask[r];
        const uint2 q0 = q[(size_t)r * 64 + lane];
        const float4 D0 = dmud[l0 * 64 + lane], C0 = dmuc[l0 * 64 + lane];
        const v2f al0 = __builtin_amdgcn_cvt_pk_f32_fp8((int)q0.x, false), ah0 = __builtin_amdgcn_cvt_pk_f32_fp8((int)q0.x, true);
        const v2f bl0 = __builtin_amdgcn_cvt_pk_f32_fp8((int)q0.y, false), bh0 = __builtin_amdgcn_cvt_pk_f32_fp8((int)q0.y, true);
        float dd0 = al0.x * D0.x + al0.y * D0.y + ah0.x * D0.z + ah0.y * D0.w;
        float dc0 = bl0.x * C0.x + bl0.y * C0.y + bh0.x * C0.z + bh0.y * C0.w;
        dd0 = wave_sum_nb(dd0); dc0 = wave_sum_nb(dc0);
        q_commit(dd0, dc0, l0, isl63, lt, lc);
    }
    __syncthreads();
    if (tid < K1) {
        atomicAdd((int*)ws + LT_OFF + tid, lt[tid]);
        atomicAdd((int*)ws + LC_OFF + tid, lc[tid]);
    }
}

// ---- Pass 2 fallback (raw floats, diff-mu + norms) ----
__global__ __launch_bounds__(512) void k_lossraw(const float4* __restrict__ dp, const float4* __restrict__ cf,
                                                 const int* __restrict__ mask, float* __restrict__ ws,
                                                 int nBlocks, int nRows)
{
    __shared__ float4 dmud[SEG_F / 4], dmuc[SEG_F / 4];
    __shared__ int lt[K1], lc[K1];
    const int tid = threadIdx.x;
    const float4* musrc = (const float4*)(ws + MU_BASE);
    for (int i = tid; i < SEG_F / 4; i += 512) { dmud[i] = musrc[i]; dmuc[i] = musrc[SEG_F / 4 + i]; }
    if (tid < K1) { lt[tid] = 0; lc[tid] = 0; }
    __syncthreads();

    const int lane = tid & 63;
    const int wid = tid >> 6;
    const int rpb = (nRows + nBlocks - 1) / nBlocks;
    const int base = blockIdx.x * rpb;
    const int end = (base + rpb < nRows) ? base + rpb : nRows;
    const int isl63 = (lane == 63);

    for (int r = base + wid; r < end; r += 8) {
        const int l0 = mask[r];
        const float4 v0 = dp[(size_t)r * 64 + lane];
        const float4 w0 = cf[(size_t)r * 64 + lane];
        const float4 D0 = dmud[l0 * 64 + lane], C0 = dmuc[l0 * 64 + lane];
        float nd = dot4s(v0), nc = dot4s(w0);
        float dd = v0.x * D0.x + v0.y * D0.y + v0.z * D0.z + v0.w * D0.w;
        float dc = w0.x * C0.x + w0.y * C0.y + w0.z * C0.z + w0.w * C0.w;
        nd = wave_sum_nb(nd); nc = wave_sum_nb(nc);
        dd = wave_sum_nb(dd); dc = wave_sum_nb(dc);
        const float xt = dd * rsq_f(fmaxf(nd, 1e-24f)) * TAU_INV;
        const float xc = dc * rsq_f(fmaxf(nc, 1e-24f)) * TAU_INV;
        const float plt = softplus_f(xt);
        const float plc = softplus_f(xc);
        if (isl63) {
            atomicAdd(&lt[l0], (int)(plt * SCALE_L + 0.5f));
            atomicAdd(&lc[l0], (int)(plc * SCALE_L + 0.5f));
        }
    }
    __syncthreads();
    if (tid < K1) {
        atomicAdd((int*)ws + LT_OFF + tid, lt[tid]);
        atomicAdd((int*)ws + LC_OFF + tid, lc[tid]);
    }
}

// ---- finalize scalar ----
__global__ void k_final(const float* __restrict__ ws, float* __restrict__ out)
{
    const int t = threadIdx.x; // 64
    const int* LT = (const int*)ws + LT_OFF;
    const int* LC = (const int*)ws + LC_OFF;
    float vt = 0.0f, vc = 0.0f, nv = 0.0f;
    if (t >= 1 && t < K1) {
        const float cnt = ws[GCNT_OFF + t];
        if (cnt >= 3.0f) {  // MIN_PIXELS
            const float safe = fmaxf(cnt, 1.0f);
            vt = (float)LT[t] * INV_L / safe;
            vc = (float)LC[t] * INV_L / safe;
            nv = 1.0f;
        }
    }
    #pragma unroll
    for (int o = 32; o > 0; o >>= 1) {
        vt += __shfl_xor(vt, o, 64);
        vc += __shfl_xor(vc, o, 64);
        nv += __shfl_xor(nv, o, 64);
    }
    if (t == 0) {
        const float n = fmaxf(nv, 1.0f);
        out[0] = vt / n + 0.5f * (vc / n);  // LAMBDA_CF = 0.5
    }
}

extern "C" void kernel_launch(void* const* d_in, const int* in_sizes, int n_in,
                              void* d_out, int out_size, void* d_ws, size_t ws_size,
                              hipStream_t stream)
{
    const float4* dp = (const float4*)d_in[0];
    const float4* cf = (const float4*)d_in[1];
    const int* mask  = (const int*)d_in[2];
    float* ws  = (float*)d_ws;
    float* out = (float*)d_out;
    const int nRows = in_sizes[2];

    uint2* q = (uint2*)((unsigned*)ws + FP8D_BASE);
    const bool use8 = (ws_size / 4) >= (size_t)FP8D_BASE + 2 * (size_t)nRows * 64;

    if (use8)
        kA<true><<<NPART, 1024, 0, stream>>>(dp, cf, mask, ws + PART_BASE, q, NPART, nRows);
    else
        kA<false><<<NPART, 1024, 0, stream>>>(dp, cf, mask, ws + PART_BASE, q, NPART, nRows);
    kRed<<<dim3(34, NGRP), 256, 0, stream>>>(ws + PART_BASE, ws + GRED_BASE, NPART);
    k_mu<<<K1, 256, 0, stream>>>(ws, NPART);
    const int nB3 = 1024;
    if (use8)
        k_loss8<<<nB3, 512, 0, stream>>>(q, mask, ws, nB3, nRows);
    else
        k_lossraw<<<nB3, 512, 0, stream>>>(dp, cf, mask, ws, nB3, nRows);
    k_final<<<1, 64, 0, stream>>>(ws, out);
}